// Round 11
// baseline (398.531 us; speedup 1.0000x reference)
//
#include <hip/hip_runtime.h>
#include <hip/hip_bf16.h>

typedef __attribute__((ext_vector_type(8))) short short8;
typedef __attribute__((ext_vector_type(4))) float f32x4;
typedef __attribute__((ext_vector_type(4))) unsigned int uint4v;
typedef __attribute__((ext_vector_type(4))) int int4v;

#define MFMA16(a,b,c) __builtin_amdgcn_mfma_f32_16x16x32_bf16((a),(b),(c),0,0,0)

#define GLOAD_LDS16(g, l) \
    __builtin_amdgcn_global_load_lds((const __attribute__((address_space(1))) void*)(g), \
                                     (__attribute__((address_space(3))) void*)(l), 16, 0, 0)

// RNE fp32->bf16 (one-time weight packing)
__device__ __forceinline__ unsigned short f2bf(float f){
    union { float f; unsigned int u; } c; c.f = f;
    unsigned int u = c.u;
    u = (u + 0x7fffu + ((u >> 16) & 1u)) >> 16;
    return (unsigned short)u;
}
__device__ __forceinline__ float bf2f(unsigned short s){
    union { unsigned int u; float f; } c; c.u = ((unsigned int)s) << 16;
    return c.f;
}

// truncation split: hi = trunc-bf16 bits, lo = bf16 bits of residual
__device__ __forceinline__ void tsplit(float f, unsigned short &h, unsigned short &l){
    unsigned int u = __builtin_bit_cast(unsigned int, f);
    float hi = __builtin_bit_cast(float, u & 0xffff0000u);
    h = (unsigned short)(u >> 16);
    l = (unsigned short)(__builtin_bit_cast(unsigned int, f - hi) >> 16);
}

// ============ image layouts ============
// GEMM A/B block (tile, kt): 16 KB, 128 rows x 128 B; 16-B slot s of row r at
// byte (s*16) ^ ((r&7)<<4). Row = 4 k-groups x [hi8|lo8].
// V^T tile block: 16 KB, 64 rows(d) x 256 B (8 key-groups x [hi8|lo8]), same XOR.
// K tile block:   same shape, FINER swizzle ksw(row)=(((row&7)+2*((row>>3)&3))&7)<<4
//   (attn's QK A-fragments read rows with row&7 in {0-3} or {4-7} only; folding
//    row bits 3-4 into the XOR restores full 8-slot bank spread).
// q rows: 256 B, 8 groups x [hi8|lo8], no swizzle.

// ---------------- pack x into plane images (truncation split) ----------------
__global__ void pack_x_kernel(const float* __restrict__ x, unsigned int* __restrict__ img){
    int tid = blockIdx.x * 256 + threadIdx.x;        // 16384*96
    int m = tid / 96, grp = tid - m * 96;
    const float* src = x + (size_t)m * 768 + grp * 8;
    f32x4 v0 = ((const f32x4*)src)[0];
    f32x4 v1 = ((const f32x4*)src)[1];
    short8 h8, l8;
    #pragma unroll
    for (int j = 0; j < 4; ++j){
        unsigned short hh, ll;
        tsplit(v0[j], hh, ll); h8[j]   = (short)hh; l8[j]   = (short)ll;
        tsplit(v1[j], hh, ll); h8[4+j] = (short)hh; l8[4+j] = (short)ll;
    }
    int mt = m >> 7, row = m & 127, kt = grp >> 2, gi = grp & 3;
    int sw = (row & 7) << 4;
    char* bp = (char*)img + ((size_t)(mt*24 + kt))*16384 + row*128;
    *(short8*)(bp + ((gi*32     ) ^ sw)) = h8;
    *(short8*)(bp + ((gi*32 + 16) ^ sw)) = l8;
}

// ---------------- pack weights into plane images (RNE split) ----------------
__global__ void pack_w_kernel(const float* __restrict__ wsrc, unsigned int* __restrict__ img, int total){
    int tid = blockIdx.x * 256 + threadIdx.x;
    if (tid >= total) return;
    int n = tid / 96, grp = tid - n * 96;
    const float* src = wsrc + (size_t)n * 768 + grp * 8;
    f32x4 v0 = ((const f32x4*)src)[0];
    f32x4 v1 = ((const f32x4*)src)[1];
    short8 h8, l8;
    #pragma unroll
    for (int j = 0; j < 4; ++j){
        unsigned short hh = f2bf(v0[j]);
        h8[j] = (short)hh; l8[j] = (short)f2bf(v0[j] - bf2f(hh));
        hh = f2bf(v1[j]);
        h8[4+j] = (short)hh; l8[4+j] = (short)f2bf(v1[j] - bf2f(hh));
    }
    int jt = n >> 7, row = n & 127, kt = grp >> 2, gi = grp & 3;
    int sw = (row & 7) << 4;
    char* bp = (char*)img + ((size_t)(jt*24 + kt))*16384 + row*128;
    *(short8*)(bp + ((gi*32     ) ^ sw)) = h8;
    *(short8*)(bp + ((gi*32 + 16) ^ sw)) = l8;
}

// ---------------- combined bias precompute: biasC = adj + table[bond] ----------------
__global__ void bias_kernel(const int* __restrict__ adj, const int* __restrict__ bond,
                            const float* __restrict__ table, float* __restrict__ biasC, int n4){
    int i = blockIdx.x * 256 + threadIdx.x;
    if (i >= n4) return;
    int4v a  = ((const int4v*)adj)[i];
    int4v bd = ((const int4v*)bond)[i];
    const float t1 = table[1], t2 = table[2], t3 = table[3], t4 = table[4];
    f32x4 o;
    #pragma unroll
    for (int j = 0; j < 4; ++j){
        int bv = bd[j];
        float tb = (bv == 1) ? t1 : (bv == 2) ? t2 : (bv == 3) ? t3 : (bv == 4) ? t4 : 0.0f;
        o[j] = (float)a[j] + tb;
    }
    ((f32x4*)biasC)[i] = o;
}

// ---------------- split-bf16 GEMM from plane images (m97 structure) ----------------
// 128x128 tile, BK=32, 4 waves, single 32KB LDS buffer, global_load_lds staging.
// __launch_bounds__(256,4): VGPR cap 128 > 64 actual -> no spill (r9 lesson:
// (256,5) capped ~96-102 and spilled acc -> 1.3 GB scratch writes, 560us).
template<int EMODE>
__global__ __launch_bounds__(256, 4)
void gemm_img(const unsigned int* __restrict__ Aimg, const unsigned int* __restrict__ Bimg,
              const float* __restrict__ bias, int NT, int RPX,
              float* __restrict__ C, int N,
              char* __restrict__ qo, char* __restrict__ ko, char* __restrict__ vo)
{
    __shared__ unsigned int lds[8192];   // A: [0..4095], B: [4096..8191]

    const int lin = blockIdx.x;
    const int xcd = lin & 7, idx = lin >> 3;
    const int grp  = idx / (RPX * 6);
    const int rem  = idx - grp * (RPX * 6);
    const int rowL = rem / 6, c6 = rem - rowL * 6;
    const int colT = grp * 6 + c6;
    const int mt = xcd * RPX + rowL;
    const int m0 = mt << 7, j0 = colT << 7;

    const int t = threadIdx.x, l = t & 63, w = t >> 6;
    const int c = l & 15, g = l >> 4;
    const int wr = (w >> 1) * 64, wc2 = (w & 1) * 64;

    const unsigned int* Ablk = Aimg + (size_t)mt   * NT * 4096;
    const unsigned int* Bblk = Bimg + (size_t)colT * NT * 4096;

    f32x4 acc[4][4] = {};

    for (int kt = 0; kt < NT; ++kt){
        const unsigned int* As = Ablk + kt*4096 + t*4;
        const unsigned int* Bs = Bblk + kt*4096 + t*4;
        unsigned int* Ad = lds + t*4;
        unsigned int* Bd = lds + 4096 + t*4;
        #pragma unroll
        for (int i = 0; i < 4; ++i){
            GLOAD_LDS16(As + i*1024, Ad + i*1024);
            GLOAD_LDS16(Bs + i*1024, Bd + i*1024);
        }
        __syncthreads();

        short8 bh[4], bl[4];
        #pragma unroll
        for (int fc = 0; fc < 4; ++fc){
            int row = wc2 + fc*16 + c;
            int sw = (row & 7) << 4;
            const char* p = (const char*)(lds + 4096) + row*128;
            bh[fc] = *(const short8*)(p + ((g*32     ) ^ sw));
            bl[fc] = *(const short8*)(p + ((g*32 + 16) ^ sw));
        }
        #pragma unroll
        for (int fr = 0; fr < 4; ++fr){
            int row = wr + fr*16 + c;
            int sw = (row & 7) << 4;
            const char* p = (const char*)lds + row*128;
            short8 ah = *(const short8*)(p + ((g*32     ) ^ sw));
            short8 al = *(const short8*)(p + ((g*32 + 16) ^ sw));
            __builtin_amdgcn_s_setprio(1);
            #pragma unroll
            for (int fc = 0; fc < 4; ++fc){
                acc[fr][fc] = MFMA16(ah, bh[fc], acc[fr][fc]);
                acc[fr][fc] = MFMA16(ah, bl[fc], acc[fr][fc]);
                acc[fr][fc] = MFMA16(al, bh[fc], acc[fr][fc]);
            }
            __builtin_amdgcn_s_setprio(0);
        }
        __syncthreads();
    }

    // ---- epilogue ----
    #pragma unroll
    for (int fr = 0; fr < 4; ++fr){
        #pragma unroll
        for (int fc = 0; fc < 4; ++fc){
            #pragma unroll
            for (int r = 0; r < 4; ++r){
                int m = m0 + wr + fr*16 + g*4 + r;
                int j = j0 + wc2 + fc*16 + c;
                float val = acc[fr][fc][r] + bias[j];
                if constexpr (EMODE == 0){
                    C[(size_t)m * N + j] = val;
                } else {
                    int sec = j / 768;
                    int off = j - sec * 768;
                    int head = off >> 6, d = off & 63;
                    int bb = m >> 9, n = m & 511;
                    int bh2 = bb * 12 + head;
                    unsigned short hh, ll;
                    tsplit(val, hh, ll);
                    if (sec == 0) {
                        char* p = qo + ((size_t)bh2*512 + n)*256 + (d>>3)*32 + (d&7)*2;
                        *(unsigned short*)(p     ) = hh;
                        *(unsigned short*)(p + 16) = ll;
                    } else if (sec == 1) {
                        // K tile-image: finer swizzle (see header comment)
                        int row = n & 63;
                        int ksw = (((row & 7) + (((row >> 3) & 3) << 1)) & 7) << 4;
                        char* p = ko + (size_t)(bh2*8 + (n>>6))*16384 + row*256;
                        *(unsigned short*)(p + ((((d>>3)*32)     ) ^ ksw) + (d&7)*2) = hh;
                        *(unsigned short*)(p + ((((d>>3)*32) + 16) ^ ksw) + (d&7)*2) = ll;
                    } else {
                        // V^T tile-image: block (bh, n>>6), row=d, col=key
                        int col = n & 63, sw = (d & 7) << 4;
                        char* p = vo + (size_t)(bh2*8 + (n>>6))*16384 + d*256;
                        *(unsigned short*)(p + ((((col>>3)*32)     ) ^ sw) + (col&7)*2) = hh;
                        *(unsigned short*)(p + ((((col>>3)*32) + 16) ^ sw) + (col&7)*2) = ll;
                    }
                }
            }
        }
    }
}

// ---------------- fused flash attention: swapped QK^T, 2 q-blocks per wave ----------------
// Grid 1536, XCD-chunked. Block covers 128 q-rows: 4 waves x 2 q-blocks of 16.
// Each K/V LDS fragment read now feeds 2x the MFMAs (12 / 6) -> LDS pipe halved.
// key(fc, g, r) = (fc>>1)*32 + g*8 + (fc&1)*4 + r (per q-block, as before).
__global__ __launch_bounds__(256, 3)
void attn_kernel(const char* __restrict__ qb,
                 const unsigned int* __restrict__ kimg,
                 const unsigned int* __restrict__ vimg,
                 const float* __restrict__ biasC,
                 char* __restrict__ oimg)
{
    __shared__ unsigned int Kt[4096];
    __shared__ unsigned int Vt[4096];

    const int lin = blockIdx.x;
    const int xcd = lin & 7, m_ = lin >> 3;
    const int bgrp = m_ / 48, r_ = m_ - bgrp * 48;   // 48 = 12 heads x 4 q-tiles
    const int b = (bgrp << 3) | xcd;
    const int h = r_ >> 2, qt = r_ & 3;
    const int bh = b * 12 + h, q0 = qt * 128;

    const int t = threadIdx.x, l = t & 63, w = t >> 6;
    const int c = l & 15, g = l >> 4;

    // Q fragments (B-operand) for 2 q-blocks of 16 rows each
    short8 qh[2][2], ql[2][2];
    #pragma unroll
    for (int qk = 0; qk < 2; ++qk){
        int qrow = q0 + w*32 + qk*16 + c;
        const char* qp = qb + ((size_t)bh*512 + qrow)*256;
        #pragma unroll
        for (int ks = 0; ks < 2; ++ks){
            qh[qk][ks] = *(const short8*)(qp + ks*128 + g*32);
            ql[qk][ks] = *(const short8*)(qp + ks*128 + g*32 + 16);
        }
    }

    f32x4 O[2][4] = {};
    float m_run[2] = {-3e38f, -3e38f};
    float l_run[2] = {0.f, 0.f};

    const float* biasRow0 = biasC + ((size_t)b * 512 + (q0 + w*32 + c)) * 512;
    const float* biasRow1 = biasRow0 + (size_t)16 * 512;

    for (int kt = 0; kt < 8; ++kt){
        // ---- stage K and V^T tiles: pure DMA ----
        {
            const unsigned int* kg = kimg + (size_t)(bh*8 + kt)*4096 + t*4;
            const unsigned int* vg = vimg + (size_t)(bh*8 + kt)*4096 + t*4;
            #pragma unroll
            for (int i = 0; i < 4; ++i){
                GLOAD_LDS16(kg + i*1024, &Kt[t*4 + i*1024]);
                GLOAD_LDS16(vg + i*1024, &Vt[t*4 + i*1024]);
            }
        }

        // ---- combined bias: 8 vector loads (2 q-blocks), issued pre-barrier ----
        f32x4 bia[2][4];
        #pragma unroll
        for (int fc = 0; fc < 4; ++fc){
            int keyb = kt*64 + (fc>>1)*32 + g*8 + ((fc&1)<<2);
            bia[0][fc] = *(const f32x4*)(biasRow0 + keyb);
            bia[1][fc] = *(const f32x4*)(biasRow1 + keyb);
        }
        __syncthreads();

        // ---- S^T = K·Q for both q-blocks: each K-frag read feeds 12 MFMAs ----
        f32x4 S[2][4] = {};
        #pragma unroll
        for (int fc = 0; fc < 4; ++fc){
            int row = (fc>>1)*32 + ((c>>2)<<3) + ((fc&1)<<2) + (c&3);
            int ksw = (((row & 7) + (((row >> 3) & 3) << 1)) & 7) << 4;
            const char* kp = (const char*)Kt + row*256;
            short8 kbh0 = *(const short8*)(kp + ((g*32           ) ^ ksw));
            short8 kbl0 = *(const short8*)(kp + ((g*32 + 16      ) ^ ksw));
            short8 kbh1 = *(const short8*)(kp + ((128 + g*32     ) ^ ksw));
            short8 kbl1 = *(const short8*)(kp + ((128 + g*32 + 16) ^ ksw));
            __builtin_amdgcn_s_setprio(1);
            #pragma unroll
            for (int qk = 0; qk < 2; ++qk){
                S[qk][fc] = MFMA16(kbh0, qh[qk][0], S[qk][fc]);
                S[qk][fc] = MFMA16(kbl0, qh[qk][0], S[qk][fc]);
                S[qk][fc] = MFMA16(kbh0, ql[qk][0], S[qk][fc]);
                S[qk][fc] = MFMA16(kbh1, qh[qk][1], S[qk][fc]);
                S[qk][fc] = MFMA16(kbl1, qh[qk][1], S[qk][fc]);
                S[qk][fc] = MFMA16(kbh1, ql[qk][1], S[qk][fc]);
            }
            __builtin_amdgcn_s_setprio(0);
        }

        // ---- per-q-block: scale + bias + mask, softmax, rescale, pack ----
        short8 pah[2][2], pal[2][2];
        #pragma unroll
        for (int qk = 0; qk < 2; ++qk){
            float p[4][4];
            float pmax = -3e38f;
            #pragma unroll
            for (int fc = 0; fc < 4; ++fc){
                #pragma unroll
                for (int r = 0; r < 4; ++r){
                    float val = fmaf(S[qk][fc][r], 0.125f, bia[qk][fc][r]);
                    if (val == 0.0f) val = -1e9f;
                    p[fc][r] = val;
                    pmax = fmaxf(pmax, val);
                }
            }
            pmax = fmaxf(pmax, __shfl_xor(pmax, 16));
            pmax = fmaxf(pmax, __shfl_xor(pmax, 32));
            float mn = fmaxf(m_run[qk], pmax);
            float corr = __expf(m_run[qk] - mn);
            float rs = 0.0f;
            #pragma unroll
            for (int fc = 0; fc < 4; ++fc){
                #pragma unroll
                for (int r = 0; r < 4; ++r){
                    float e = __expf(p[fc][r] - mn);
                    p[fc][r] = e;
                    rs += e;
                }
            }
            rs += __shfl_xor(rs, 16);
            rs += __shfl_xor(rs, 32);
            l_run[qk] = l_run[qk] * corr + rs;
            m_run[qk] = mn;

            #pragma unroll
            for (int r = 0; r < 4; ++r){
                float cr = __shfl(corr, (l & 48) | (g*4 + r));
                O[qk][0][r] *= cr; O[qk][1][r] *= cr;
                O[qk][2][r] *= cr; O[qk][3][r] *= cr;
            }

            #pragma unroll
            for (int ks = 0; ks < 2; ++ks){
                uint4v ph, plo;
                #pragma unroll
                for (int j = 0; j < 4; ++j){
                    const int fc = 2*ks + (j >> 1);
                    const int r0 = (j & 1) * 2;
                    float a  = p[fc][r0], bq = p[fc][r0 + 1];
                    unsigned int ua = __builtin_bit_cast(unsigned int, a);
                    unsigned int ub = __builtin_bit_cast(unsigned int, bq);
                    float ra = a  - __builtin_bit_cast(float, ua & 0xffff0000u);
                    float rb = bq - __builtin_bit_cast(float, ub & 0xffff0000u);
                    ph[j]  = __builtin_amdgcn_perm(ub, ua, 0x07060302u);
                    plo[j] = __builtin_amdgcn_perm(__builtin_bit_cast(unsigned int, rb),
                                                   __builtin_bit_cast(unsigned int, ra), 0x07060302u);
                }
                pah[qk][ks] = __builtin_bit_cast(short8, ph);
                pal[qk][ks] = __builtin_bit_cast(short8, plo);
            }
        }

        // ---- O += P·V for both q-blocks: each V-frag read feeds 6 MFMAs ----
        #pragma unroll
        for (int ks = 0; ks < 2; ++ks){
            #pragma unroll
            for (int hf = 0; hf < 4; ++hf){
                int row = hf*16 + c;
                int sw = (row & 7) << 4;
                const char* vp = (const char*)Vt + row*256;
                short8 vbh = *(const short8*)(vp + ((ks*128 + g*32     ) ^ sw));
                short8 vbl = *(const short8*)(vp + ((ks*128 + g*32 + 16) ^ sw));
                __builtin_amdgcn_s_setprio(1);
                #pragma unroll
                for (int qk = 0; qk < 2; ++qk){
                    O[qk][hf] = MFMA16(pah[qk][ks], vbh, O[qk][hf]);
                    O[qk][hf] = MFMA16(pah[qk][ks], vbl, O[qk][hf]);
                    O[qk][hf] = MFMA16(pal[qk][ks], vbh, O[qk][hf]);
                }
                __builtin_amdgcn_s_setprio(0);
            }
        }
        __syncthreads();
    }

    // ---- epilogue: write gemm2 A-images (plane layout), both q-blocks ----
    #pragma unroll
    for (int qk = 0; qk < 2; ++qk){
        float linv = 1.0f / l_run[qk];
        #pragma unroll
        for (int r = 0; r < 4; ++r){
            float inv = __shfl(linv, (l & 48) | (g*4 + r));
            int m = b*512 + q0 + w*32 + qk*16 + g*4 + r;
            int mt = m >> 7, mrow2 = m & 127;
            int swz = (mrow2 & 7) << 4;
            char* rowp = oimg + ((size_t)mt*24)*16384 + (size_t)mrow2*128;
            #pragma unroll
            for (int hf = 0; hf < 4; ++hf){
                int e = h*64 + hf*16 + c;
                int kt2 = e >> 5, gi = (e >> 3) & 3, pos = e & 7;
                unsigned short hh, ll;
                tsplit(O[qk][hf][r] * inv, hh, ll);
                char* pp = rowp + (size_t)kt2*16384;
                *(unsigned short*)(pp + (((gi*32)     ) ^ swz) + pos*2) = hh;
                *(unsigned short*)(pp + (((gi*32) + 16) ^ swz) + pos*2) = ll;
            }
        }
    }
}

extern "C" void kernel_launch(void* const* d_in, const int* in_sizes, int n_in,
                              void* d_out, int out_size, void* d_ws, size_t ws_size,
                              hipStream_t stream)
{
    const float* x     = (const float*)d_in[0];
    const int*   adj   = (const int*)d_in[1];
    const int*   bond  = (const int*)d_in[2];
    const float* qkv_w = (const float*)d_in[4];
    const float* qkv_b = (const float*)d_in[5];
    const float* out_w = (const float*)d_in[6];
    const float* out_b = (const float*)d_in[7];
    const float* btab  = (const float*)d_in[8];
    float* out = (float*)d_out;

    const size_t QKV = 12582912;                 // 32*12*512*64 u32-equivalents
    unsigned int* q   = (unsigned int*)d_ws;     // q row-planes (48 MB)
    unsigned int* k   = q  + QKV;                // K tile-images
    unsigned int* vt  = k  + QKV;                // V^T tile-images
    unsigned int* r1  = vt + QKV;                // x-images, then o-images
    unsigned int* w2i = r1 + QKV;                // 589824 u32
    unsigned int* r2  = w2i + 589824;            // w1 images (7 MB), then biasC (33.5 MB)
    unsigned int* w1i = r2;
    float* biasC      = (float*)r2;

    dim3 blk(256);
    pack_w_kernel<<<dim3(864), blk, 0, stream>>>(qkv_w, w1i, 2304*96);
    pack_w_kernel<<<dim3(288), blk, 0, stream>>>(out_w, w2i, 768*96);
    pack_x_kernel<<<dim3(6144), blk, 0, stream>>>(x, r1);

    // QKV projection: 2304 blocks = 8 XCDs x (3 col-groups x 16 rows x 6 cols)
    gemm_img<1><<<dim3(2304), blk, 0, stream>>>(r1, w1i, qkv_b, 24, 16,
                                                nullptr, 2304, (char*)q, (char*)k, (char*)vt);

    // biasC overwrites w1 images -> strictly after gemm1 (stream order)
    bias_kernel<<<dim3(8192), blk, 0, stream>>>(adj, bond, btab, biasC, (32*512*512)/4);

    // fused attention: 1536 blocks = 8 XCDs x 4 batches x 12 heads x 4 q-tiles(128)
    attn_kernel<<<dim3(1536), blk, 0, stream>>>((const char*)q, k, vt, biasC, (char*)r1);

    // output projection: 768 blocks = 8 XCDs x (16 rows x 6 cols)
    gemm_img<0><<<dim3(768), blk, 0, stream>>>(r1, w2i, out_b, 24, 16,
                                               out, 768, nullptr, nullptr, nullptr);
}

// Round 12
// 389.110 us; speedup vs baseline: 1.0242x; 1.0242x over previous
//
#include <hip/hip_runtime.h>
#include <hip/hip_bf16.h>

typedef __attribute__((ext_vector_type(8))) short short8;
typedef __attribute__((ext_vector_type(4))) float f32x4;
typedef __attribute__((ext_vector_type(4))) unsigned int uint4v;
typedef __attribute__((ext_vector_type(4))) int int4v;

#define MFMA16(a,b,c) __builtin_amdgcn_mfma_f32_16x16x32_bf16((a),(b),(c),0,0,0)

#define GLOAD_LDS16(g, l) \
    __builtin_amdgcn_global_load_lds((const __attribute__((address_space(1))) void*)(g), \
                                     (__attribute__((address_space(3))) void*)(l), 16, 0, 0)

// RNE fp32->bf16 (one-time weight packing)
__device__ __forceinline__ unsigned short f2bf(float f){
    union { float f; unsigned int u; } c; c.f = f;
    unsigned int u = c.u;
    u = (u + 0x7fffu + ((u >> 16) & 1u)) >> 16;
    return (unsigned short)u;
}
__device__ __forceinline__ float bf2f(unsigned short s){
    union { unsigned int u; float f; } c; c.u = ((unsigned int)s) << 16;
    return c.f;
}

// truncation split: hi = trunc-bf16 bits, lo = bf16 bits of residual
__device__ __forceinline__ void tsplit(float f, unsigned short &h, unsigned short &l){
    unsigned int u = __builtin_bit_cast(unsigned int, f);
    float hi = __builtin_bit_cast(float, u & 0xffff0000u);
    h = (unsigned short)(u >> 16);
    l = (unsigned short)(__builtin_bit_cast(unsigned int, f - hi) >> 16);
}

// ============ image layouts ============
// GEMM A/B block (tile, kt): 16 KB, 128 rows x 128 B; 16-B slot s of row r at
// byte (s*16) ^ ((r&7)<<4). Row = 4 k-groups x [hi8|lo8].
// V^T tile block: 16 KB, 64 rows(d) x 256 B (8 key-groups x [hi8|lo8]), same XOR.
// K tile block:   same shape, FINER swizzle ksw(row)=(((row&7)+2*((row>>3)&3))&7)<<4
//   (attn's QK A-fragments read rows with row&7 in {0-3} or {4-7} only; folding
//    row bits 3-4 into the XOR restores full 8-slot bank spread).
// q rows: 256 B, 8 groups x [hi8|lo8], no swizzle.

// ---------------- pack x into plane images (truncation split) ----------------
__global__ void pack_x_kernel(const float* __restrict__ x, unsigned int* __restrict__ img){
    int tid = blockIdx.x * 256 + threadIdx.x;        // 16384*96
    int m = tid / 96, grp = tid - m * 96;
    const float* src = x + (size_t)m * 768 + grp * 8;
    f32x4 v0 = ((const f32x4*)src)[0];
    f32x4 v1 = ((const f32x4*)src)[1];
    short8 h8, l8;
    #pragma unroll
    for (int j = 0; j < 4; ++j){
        unsigned short hh, ll;
        tsplit(v0[j], hh, ll); h8[j]   = (short)hh; l8[j]   = (short)ll;
        tsplit(v1[j], hh, ll); h8[4+j] = (short)hh; l8[4+j] = (short)ll;
    }
    int mt = m >> 7, row = m & 127, kt = grp >> 2, gi = grp & 3;
    int sw = (row & 7) << 4;
    char* bp = (char*)img + ((size_t)(mt*24 + kt))*16384 + row*128;
    *(short8*)(bp + ((gi*32     ) ^ sw)) = h8;
    *(short8*)(bp + ((gi*32 + 16) ^ sw)) = l8;
}

// ---------------- pack weights into plane images (RNE split) ----------------
__global__ void pack_w_kernel(const float* __restrict__ wsrc, unsigned int* __restrict__ img, int total){
    int tid = blockIdx.x * 256 + threadIdx.x;
    if (tid >= total) return;
    int n = tid / 96, grp = tid - n * 96;
    const float* src = wsrc + (size_t)n * 768 + grp * 8;
    f32x4 v0 = ((const f32x4*)src)[0];
    f32x4 v1 = ((const f32x4*)src)[1];
    short8 h8, l8;
    #pragma unroll
    for (int j = 0; j < 4; ++j){
        unsigned short hh = f2bf(v0[j]);
        h8[j] = (short)hh; l8[j] = (short)f2bf(v0[j] - bf2f(hh));
        hh = f2bf(v1[j]);
        h8[4+j] = (short)hh; l8[4+j] = (short)f2bf(v1[j] - bf2f(hh));
    }
    int jt = n >> 7, row = n & 127, kt = grp >> 2, gi = grp & 3;
    int sw = (row & 7) << 4;
    char* bp = (char*)img + ((size_t)(jt*24 + kt))*16384 + row*128;
    *(short8*)(bp + ((gi*32     ) ^ sw)) = h8;
    *(short8*)(bp + ((gi*32 + 16) ^ sw)) = l8;
}

// ---------------- combined bias precompute: biasC = adj + table[bond] ----------------
__global__ void bias_kernel(const int* __restrict__ adj, const int* __restrict__ bond,
                            const float* __restrict__ table, float* __restrict__ biasC, int n4){
    int i = blockIdx.x * 256 + threadIdx.x;
    if (i >= n4) return;
    int4v a  = ((const int4v*)adj)[i];
    int4v bd = ((const int4v*)bond)[i];
    const float t1 = table[1], t2 = table[2], t3 = table[3], t4 = table[4];
    f32x4 o;
    #pragma unroll
    for (int j = 0; j < 4; ++j){
        int bv = bd[j];
        float tb = (bv == 1) ? t1 : (bv == 2) ? t2 : (bv == 3) ? t3 : (bv == 4) ? t4 : 0.0f;
        o[j] = (float)a[j] + tb;
    }
    ((f32x4*)biasC)[i] = o;
}

// ---------------- split-bf16 GEMM from plane images (m97 structure) ----------------
// 128x128 tile, BK=32, 4 waves, single 32KB LDS buffer, global_load_lds staging.
// __launch_bounds__(256,4): VGPR cap 128 > 64 actual -> no spill (r9 lesson:
// (256,5) capped ~96-102 and spilled acc -> 1.3 GB scratch writes, 560us).
template<int EMODE>
__global__ __launch_bounds__(256, 4)
void gemm_img(const unsigned int* __restrict__ Aimg, const unsigned int* __restrict__ Bimg,
              const float* __restrict__ bias, int NT, int RPX,
              float* __restrict__ C, int N,
              char* __restrict__ qo, char* __restrict__ ko, char* __restrict__ vo)
{
    __shared__ unsigned int lds[8192];   // A: [0..4095], B: [4096..8191]

    const int lin = blockIdx.x;
    const int xcd = lin & 7, idx = lin >> 3;
    const int grp  = idx / (RPX * 6);
    const int rem  = idx - grp * (RPX * 6);
    const int rowL = rem / 6, c6 = rem - rowL * 6;
    const int colT = grp * 6 + c6;
    const int mt = xcd * RPX + rowL;
    const int m0 = mt << 7, j0 = colT << 7;

    const int t = threadIdx.x, l = t & 63, w = t >> 6;
    const int c = l & 15, g = l >> 4;
    const int wr = (w >> 1) * 64, wc2 = (w & 1) * 64;

    const unsigned int* Ablk = Aimg + (size_t)mt   * NT * 4096;
    const unsigned int* Bblk = Bimg + (size_t)colT * NT * 4096;

    f32x4 acc[4][4] = {};

    for (int kt = 0; kt < NT; ++kt){
        const unsigned int* As = Ablk + kt*4096 + t*4;
        const unsigned int* Bs = Bblk + kt*4096 + t*4;
        unsigned int* Ad = lds + t*4;
        unsigned int* Bd = lds + 4096 + t*4;
        #pragma unroll
        for (int i = 0; i < 4; ++i){
            GLOAD_LDS16(As + i*1024, Ad + i*1024);
            GLOAD_LDS16(Bs + i*1024, Bd + i*1024);
        }
        __syncthreads();

        short8 bh[4], bl[4];
        #pragma unroll
        for (int fc = 0; fc < 4; ++fc){
            int row = wc2 + fc*16 + c;
            int sw = (row & 7) << 4;
            const char* p = (const char*)(lds + 4096) + row*128;
            bh[fc] = *(const short8*)(p + ((g*32     ) ^ sw));
            bl[fc] = *(const short8*)(p + ((g*32 + 16) ^ sw));
        }
        #pragma unroll
        for (int fr = 0; fr < 4; ++fr){
            int row = wr + fr*16 + c;
            int sw = (row & 7) << 4;
            const char* p = (const char*)lds + row*128;
            short8 ah = *(const short8*)(p + ((g*32     ) ^ sw));
            short8 al = *(const short8*)(p + ((g*32 + 16) ^ sw));
            __builtin_amdgcn_s_setprio(1);
            #pragma unroll
            for (int fc = 0; fc < 4; ++fc){
                acc[fr][fc] = MFMA16(ah, bh[fc], acc[fr][fc]);
                acc[fr][fc] = MFMA16(ah, bl[fc], acc[fr][fc]);
                acc[fr][fc] = MFMA16(al, bh[fc], acc[fr][fc]);
            }
            __builtin_amdgcn_s_setprio(0);
        }
        __syncthreads();
    }

    // ---- epilogue ----
    #pragma unroll
    for (int fr = 0; fr < 4; ++fr){
        #pragma unroll
        for (int fc = 0; fc < 4; ++fc){
            #pragma unroll
            for (int r = 0; r < 4; ++r){
                int m = m0 + wr + fr*16 + g*4 + r;
                int j = j0 + wc2 + fc*16 + c;
                float val = acc[fr][fc][r] + bias[j];
                if constexpr (EMODE == 0){
                    C[(size_t)m * N + j] = val;
                } else {
                    int sec = j / 768;
                    int off = j - sec * 768;
                    int head = off >> 6, d = off & 63;
                    int bb = m >> 9, n = m & 511;
                    int bh2 = bb * 12 + head;
                    unsigned short hh, ll;
                    tsplit(val, hh, ll);
                    if (sec == 0) {
                        char* p = qo + ((size_t)bh2*512 + n)*256 + (d>>3)*32 + (d&7)*2;
                        *(unsigned short*)(p     ) = hh;
                        *(unsigned short*)(p + 16) = ll;
                    } else if (sec == 1) {
                        // K tile-image: finer swizzle (see header comment)
                        int row = n & 63;
                        int ksw = (((row & 7) + (((row >> 3) & 3) << 1)) & 7) << 4;
                        char* p = ko + (size_t)(bh2*8 + (n>>6))*16384 + row*256;
                        *(unsigned short*)(p + ((((d>>3)*32)     ) ^ ksw) + (d&7)*2) = hh;
                        *(unsigned short*)(p + ((((d>>3)*32) + 16) ^ ksw) + (d&7)*2) = ll;
                    } else {
                        // V^T tile-image: block (bh, n>>6), row=d, col=key
                        int col = n & 63, sw = (d & 7) << 4;
                        char* p = vo + (size_t)(bh2*8 + (n>>6))*16384 + d*256;
                        *(unsigned short*)(p + ((((col>>3)*32)     ) ^ sw) + (col&7)*2) = hh;
                        *(unsigned short*)(p + ((((col>>3)*32) + 16) ^ sw) + (col&7)*2) = ll;
                    }
                }
            }
        }
    }
}

// ---------------- fused flash attention: swapped QK^T, in-lane softmax ----------------
// 1D grid 3072, XCD-chunked. Each lane owns ONE q-row (q = c); its 16 S values
// are exactly its PV A-fragment keys -> P packs in-lane, no P LDS bounce.
// key(fc, g, r) = (fc>>1)*32 + g*8 + (fc&1)*4 + r.
__global__ __launch_bounds__(256, 4)
void attn_kernel(const char* __restrict__ qb,
                 const unsigned int* __restrict__ kimg,
                 const unsigned int* __restrict__ vimg,
                 const float* __restrict__ biasC,
                 char* __restrict__ oimg)
{
    __shared__ unsigned int Kt[4096];
    __shared__ unsigned int Vt[4096];

    const int lin = blockIdx.x;
    const int xcd = lin & 7, m_ = lin >> 3;
    const int bgrp = m_ / 96, r_ = m_ - bgrp * 96;
    const int b = (bgrp << 3) | xcd;
    const int h = r_ >> 3, qt = r_ & 7;
    const int bh = b * 12 + h, q0 = qt * 64;

    const int t = threadIdx.x, l = t & 63, w = t >> 6;
    const int c = l & 15, g = l >> 4;

    // Q fragments (B-operand): col = c -> qrow, k-elems d = ks*32 + g*8 + i
    short8 qh[2], ql[2];
    {
        int qrow = q0 + w*16 + c;
        const char* qp = qb + ((size_t)bh*512 + qrow)*256;
        #pragma unroll
        for (int ks = 0; ks < 2; ++ks){
            qh[ks] = *(const short8*)(qp + ks*128 + g*32);
            ql[ks] = *(const short8*)(qp + ks*128 + g*32 + 16);
        }
    }

    f32x4 O[4] = {};
    float m_run = -3e38f, l_run = 0.0f;

    const float* biasRow = biasC + ((size_t)b * 512 + (q0 + w*16 + c)) * 512;

    for (int kt = 0; kt < 8; ++kt){
        // ---- stage K and V^T tiles: pure DMA ----
        {
            const unsigned int* kg = kimg + (size_t)(bh*8 + kt)*4096 + t*4;
            const unsigned int* vg = vimg + (size_t)(bh*8 + kt)*4096 + t*4;
            #pragma unroll
            for (int i = 0; i < 4; ++i){
                GLOAD_LDS16(kg + i*1024, &Kt[t*4 + i*1024]);
                GLOAD_LDS16(vg + i*1024, &Vt[t*4 + i*1024]);
            }
        }

        // ---- combined bias: 4 vector loads (keys consecutive per fragment) ----
        f32x4 bia[4];
        #pragma unroll
        for (int fc = 0; fc < 4; ++fc){
            int keyb = kt*64 + (fc>>1)*32 + g*8 + ((fc&1)<<2);
            bia[fc] = *(const f32x4*)(biasRow + keyb);
        }
        __syncthreads();

        // ---- S^T = K·Q : lane (g,c) gets S[fc][r] for q=c, key=key(fc,g,r) ----
        f32x4 S[4] = {};
        #pragma unroll
        for (int fc = 0; fc < 4; ++fc){
            int row = (fc>>1)*32 + ((c>>2)<<3) + ((fc&1)<<2) + (c&3);
            int ksw = (((row & 7) + (((row >> 3) & 3) << 1)) & 7) << 4;
            const char* kp = (const char*)Kt + row*256;
            short8 kbh0 = *(const short8*)(kp + ((g*32           ) ^ ksw));
            short8 kbl0 = *(const short8*)(kp + ((g*32 + 16      ) ^ ksw));
            short8 kbh1 = *(const short8*)(kp + ((128 + g*32     ) ^ ksw));
            short8 kbl1 = *(const short8*)(kp + ((128 + g*32 + 16) ^ ksw));
            __builtin_amdgcn_s_setprio(1);
            S[fc] = MFMA16(kbh0, qh[0], S[fc]);
            S[fc] = MFMA16(kbl0, qh[0], S[fc]);
            S[fc] = MFMA16(kbh0, ql[0], S[fc]);
            S[fc] = MFMA16(kbh1, qh[1], S[fc]);
            S[fc] = MFMA16(kbl1, qh[1], S[fc]);
            S[fc] = MFMA16(kbh1, ql[1], S[fc]);
            __builtin_amdgcn_s_setprio(0);
        }

        // ---- scale + bias + masked_fill, in-lane max ----
        float p[4][4];
        float pmax = -3e38f;
        #pragma unroll
        for (int fc = 0; fc < 4; ++fc){
            #pragma unroll
            for (int r = 0; r < 4; ++r){
                float val = fmaf(S[fc][r], 0.125f, bia[fc][r]);
                if (val == 0.0f) val = -1e9f;
                p[fc][r] = val;
                pmax = fmaxf(pmax, val);
            }
        }
        // cross-g reduce (keys of row q=c live in the 4 g-groups at same c)
        pmax = fmaxf(pmax, __shfl_xor(pmax, 16));
        pmax = fmaxf(pmax, __shfl_xor(pmax, 32));
        float mn = fmaxf(m_run, pmax);
        float corr = __expf(m_run - mn);
        float rs = 0.0f;
        #pragma unroll
        for (int fc = 0; fc < 4; ++fc){
            #pragma unroll
            for (int r = 0; r < 4; ++r){
                float e = __expf(p[fc][r] - mn);
                p[fc][r] = e;
                rs += e;
            }
        }
        rs += __shfl_xor(rs, 16);
        rs += __shfl_xor(rs, 32);
        l_run = l_run * corr + rs;
        m_run = mn;

        // ---- O rescale: corr(q = g*4+r) via lane broadcast ----
        #pragma unroll
        for (int r = 0; r < 4; ++r){
            float cr = __shfl(corr, (l & 48) | (g*4 + r));
            O[0][r] *= cr; O[1][r] *= cr; O[2][r] *= cr; O[3][r] *= cr;
        }

        // ---- P pack (in-lane) + O += P·V ----
        #pragma unroll
        for (int ks = 0; ks < 2; ++ks){
            uint4v ph, plo;
            #pragma unroll
            for (int j = 0; j < 4; ++j){
                const int fc = 2*ks + (j >> 1);
                const int r0 = (j & 1) * 2;
                float a  = p[fc][r0], bq = p[fc][r0 + 1];
                unsigned int ua = __builtin_bit_cast(unsigned int, a);
                unsigned int ub = __builtin_bit_cast(unsigned int, bq);
                float ra = a  - __builtin_bit_cast(float, ua & 0xffff0000u);
                float rb = bq - __builtin_bit_cast(float, ub & 0xffff0000u);
                ph[j]  = __builtin_amdgcn_perm(ub, ua, 0x07060302u);
                plo[j] = __builtin_amdgcn_perm(__builtin_bit_cast(unsigned int, rb),
                                               __builtin_bit_cast(unsigned int, ra), 0x07060302u);
            }
            short8 pah = __builtin_bit_cast(short8, ph);
            short8 pal = __builtin_bit_cast(short8, plo);
            #pragma unroll
            for (int hf = 0; hf < 4; ++hf){
                int row = hf*16 + c;
                int sw = (row & 7) << 4;
                const char* vp = (const char*)Vt + row*256;
                short8 vbh = *(const short8*)(vp + ((ks*128 + g*32     ) ^ sw));
                short8 vbl = *(const short8*)(vp + ((ks*128 + g*32 + 16) ^ sw));
                __builtin_amdgcn_s_setprio(1);
                O[hf] = MFMA16(pah, vbh, O[hf]);
                O[hf] = MFMA16(pah, vbl, O[hf]);
                O[hf] = MFMA16(pal, vbh, O[hf]);
                __builtin_amdgcn_s_setprio(0);
            }
        }
        __syncthreads();
    }

    // ---- epilogue: write gemm2 A-images (plane layout) ----
    float linv = 1.0f / l_run;
    #pragma unroll
    for (int r = 0; r < 4; ++r){
        float inv = __shfl(linv, (l & 48) | (g*4 + r));
        int m = b*512 + q0 + w*16 + g*4 + r;
        int mt = m >> 7, mrow2 = m & 127;
        int swz = (mrow2 & 7) << 4;
        char* rowp = oimg + ((size_t)mt*24)*16384 + (size_t)mrow2*128;
        #pragma unroll
        for (int hf = 0; hf < 4; ++hf){
            int e = h*64 + hf*16 + c;
            int kt2 = e >> 5, gi = (e >> 3) & 3, pos = e & 7;
            unsigned short hh, ll;
            tsplit(O[hf][r] * inv, hh, ll);
            char* pp = rowp + (size_t)kt2*16384;
            *(unsigned short*)(pp + (((gi*32)     ) ^ swz) + pos*2) = hh;
            *(unsigned short*)(pp + (((gi*32) + 16) ^ swz) + pos*2) = ll;
        }
    }
}

extern "C" void kernel_launch(void* const* d_in, const int* in_sizes, int n_in,
                              void* d_out, int out_size, void* d_ws, size_t ws_size,
                              hipStream_t stream)
{
    const float* x     = (const float*)d_in[0];
    const int*   adj   = (const int*)d_in[1];
    const int*   bond  = (const int*)d_in[2];
    const float* qkv_w = (const float*)d_in[4];
    const float* qkv_b = (const float*)d_in[5];
    const float* out_w = (const float*)d_in[6];
    const float* out_b = (const float*)d_in[7];
    const float* btab  = (const float*)d_in[8];
    float* out = (float*)d_out;

    const size_t QKV = 12582912;                 // 32*12*512*64 u32-equivalents
    unsigned int* q   = (unsigned int*)d_ws;     // q row-planes (48 MB)
    unsigned int* k   = q  + QKV;                // K tile-images
    unsigned int* vt  = k  + QKV;                // V^T tile-images
    unsigned int* r1  = vt + QKV;                // x-images, then o-images
    unsigned int* w2i = r1 + QKV;                // 589824 u32
    unsigned int* r2  = w2i + 589824;            // w1 images (7 MB), then biasC (33.5 MB)
    unsigned int* w1i = r2;
    float* biasC      = (float*)r2;

    dim3 blk(256);
    pack_w_kernel<<<dim3(864), blk, 0, stream>>>(qkv_w, w1i, 2304*96);
    pack_w_kernel<<<dim3(288), blk, 0, stream>>>(out_w, w2i, 768*96);
    pack_x_kernel<<<dim3(6144), blk, 0, stream>>>(x, r1);

    // QKV projection: 2304 blocks = 8 XCDs x (3 col-groups x 16 rows x 6 cols)
    gemm_img<1><<<dim3(2304), blk, 0, stream>>>(r1, w1i, qkv_b, 24, 16,
                                                nullptr, 2304, (char*)q, (char*)k, (char*)vt);

    // biasC overwrites w1 images -> strictly after gemm1 (stream order)
    bias_kernel<<<dim3(8192), blk, 0, stream>>>(adj, bond, btab, biasC, (32*512*512)/4);

    // fused attention: writes o-images into r1 (x-images dead after gemm1)
    attn_kernel<<<dim3(3072), blk, 0, stream>>>((const char*)q, k, vt, biasC, (char*)r1);

    // output projection: 768 blocks = 8 XCDs x (16 rows x 6 cols)
    gemm_img<0><<<dim3(768), blk, 0, stream>>>(r1, w2i, out_b, 24, 16,
                                               out, 768, nullptr, nullptr, nullptr);
}